// Round 10
// baseline (220.613 us; speedup 1.0000x reference)
//
#include <hip/hip_runtime.h>
#include <math.h>

// GatedGCN forward, fp32 in/out. D = U = 96. 3 dispatches:
//   memset(cnt8) | k_fuse1: W-convert + Xb + newX MFMA + 8-way sub-counter CSR
//   fill | k_aggGate(512thr): CSR gather -> LDS + gate MFMA + combine.
// Evidence trail: R4/R9 -> fill is same-address atomic-serialization bound
// (16 edges/dest serialize at L2); 8 sub-counters cut depth to 2 and keep
// counter+store lines XCD-local (g=blockIdx&7). Dest-major sub-lists keep the
// region at 51.2 MB (R8: per-XCD 102 MB regions thrash L2). R6: no grid.sync.

#define DU 96
#define DU4 24
#define CAPG 16  // slots per (dest, group); per-list ~Poisson(2), P(>=17)~2e-10

typedef unsigned int uint;
typedef unsigned short ushort;
typedef __attribute__((ext_vector_type(8))) short short8;
typedef __attribute__((ext_vector_type(4))) float f32x4;

__device__ inline uint bf16r(float x) {  // fp32 -> bf16 bits, round-nearest-even
  uint u = __float_as_uint(x);
  return (u + 0x7FFFu + ((u >> 16) & 1u)) >> 16;
}

// ---------- k_fuse1: per-block W->LDS, X->Xs/Xb, newX MFMA, then CSR fill ----
__global__ __launch_bounds__(256) void k_fuse1(
    const float* __restrict__ X, const float* __restrict__ Wn,
    const float* __restrict__ bn, const float* __restrict__ Wgi,
    const float* __restrict__ Wgn, const int* __restrict__ row,
    const int* __restrict__ col, const float* __restrict__ a_vals,
    ushort* __restrict__ Xb, ushort* __restrict__ newXb,
    ushort* __restrict__ WTgi, ushort* __restrict__ WTgn,
    int* __restrict__ cnt8, int2* __restrict__ epad, int N, int E, int ntile) {
  __shared__ ushort WL[9216];     // Wn bf16, MFMA-fragment-ordered (18 KB)
  __shared__ ushort Xs[64][104];  // X tile bf16 (13 KB); reused as Y staging
  const int tid = threadIdx.x;
  const int lane = tid & 63, w = tid >> 6;
  const int m = lane & 15, q = lane >> 4;

  if ((int)blockIdx.x < ntile) {
    // blocks 0/1: emit gate weights bf16 (row-major WT[n*96+k]) for k_aggGate
    if (blockIdx.x == 0) {
      for (int i = tid; i < DU * DU; i += 256) {
        int n = i / DU, k = i % DU;
        WTgi[i] = (ushort)bf16r(Wgi[k * DU + n]);
      }
    } else if (blockIdx.x == 1) {
      for (int i = tid; i < DU * DU; i += 256) {
        int n = i / DU, k = i % DU;
        WTgn[i] = (ushort)bf16r(Wgn[k * DU + n]);
      }
    }
    // Wn -> WL in exact B-fragment order: frag (ks,t), lane, j ->
    // element k = ks*32+(lane>>4)*8+j, n = t*16+(lane&15)
    for (int idx = tid; idx < 9216; idx += 256) {
      int j = idx & 7, ln = (idx >> 3) & 63, tk = idx >> 9;  // tk = ks*6+t
      int ks = tk / 6, t = tk % 6;
      int k = ks * 32 + (ln >> 4) * 8 + j;
      int n = t * 16 + (ln & 15);
      WL[idx] = (ushort)bf16r(Wn[k * DU + n]);
    }
    // own 64 X rows -> Xs (LDS) + Xb (global)
    const int row0 = blockIdx.x * 64;
    for (int i = tid; i < 64 * 48; i += 256) {
      int r = i / 48, cu = i % 48;
      int gr = row0 + r;
      uint packed = 0;
      if (gr < N) {
        float2 v = ((const float2*)X)[(size_t)gr * 48 + cu];
        packed = bf16r(v.x) | (bf16r(v.y) << 16);
        ((uint*)Xb)[(size_t)gr * 48 + cu] = packed;
      }
      *(uint*)&Xs[r][cu * 2] = packed;
    }
    __syncthreads();

    f32x4 acc[6];
#pragma unroll
    for (int t = 0; t < 6; ++t) acc[t] = (f32x4){0.f, 0.f, 0.f, 0.f};
#pragma unroll
    for (int ks = 0; ks < 3; ++ks) {
      short8 af = *(const short8*)&Xs[w * 16 + m][ks * 32 + q * 8];
#pragma unroll
      for (int t = 0; t < 6; ++t) {
        short8 bf = *(const short8*)&WL[((ks * 6 + t) * 64 + lane) * 8];
        acc[t] = __builtin_amdgcn_mfma_f32_16x16x32_bf16(af, bf, acc[t], 0, 0, 0);
      }
    }
    __syncthreads();  // all A-frag reads done; reuse Xs as output staging
#pragma unroll
    for (int t = 0; t < 6; ++t) {
      int c = t * 16 + m;
      float bb = bn[c];
#pragma unroll
      for (int i = 0; i < 4; ++i)
        Xs[w * 16 + q * 4 + i][c] = (ushort)bf16r(acc[t][i] + bb);
    }
    __syncthreads();
    for (int i = tid; i < 64 * 48; i += 256) {
      int r = i / 48, cu = i % 48;
      int gr = row0 + r;
      if (gr < N) ((uint*)newXb)[(size_t)gr * 48 + cu] = *(uint*)&Xs[r][cu * 2];
    }
  }

  // Single-pass CSR fill with 8-way sub-counters. g = blockIdx&7 -> same XCD
  // under round-robin dispatch: counters cnt8[g*N+d] and sub-list lines
  // epad[d*128 + g*16 ..] are touched by one XCD only (128 B = 2 lines per
  // (d,g): no cross-XCD line sharing; 3.2 MB write set per XCD fits its L2).
  // Atomic serialization depth per counter: 16 -> ~2.
  {
    const int g = blockIdx.x & 7;
    int* cnt = cnt8 + (size_t)g * N;
    for (int i = blockIdx.x * 256 + tid; i < E; i += gridDim.x * 256) {
      int d = row[i];
      int slot = atomicAdd(&cnt[d], 1);
      if (slot < CAPG)  // overflow prob ~1e-10 per list; guard OOB
        epad[(size_t)d * 128 + g * CAPG + slot] =
            make_int2(col[i], __float_as_int(a_vals[i]));
    }
  }
}

// ---------- k_aggGate: CSR gather -> LDS, gate MFMA, combine (512 thr) ------
// 64 rows/block. Agg: 768 (row, 16B-chunk) tasks on 512 threads, uint4 loads.
// Gate: 8 waves = 4 row-groups x 2 col-halves, 3 MFMA acc tiles per wave.
// out = X + sigmoid(Xb@Wgi + As@Wgn + b) * (agg - X).
__global__ __launch_bounds__(512) void k_aggGate(
    const ushort* __restrict__ Xb, const ushort* __restrict__ newXb,
    const int* __restrict__ cnt8, const int2* __restrict__ epad,
    const ushort* __restrict__ WTgi, const ushort* __restrict__ WTgn,
    const float* __restrict__ bgi, const float* __restrict__ bgn,
    const float* __restrict__ X, float* __restrict__ Out, int N) {
  __shared__ ushort As[64][104];  // agg tile bf16 (13.3 KB)
  __shared__ float Gs[64][100];   // gate tile fp32 (25.6 KB)
  const int tid = threadIdx.x;
  const int lane = tid & 63;
  const int m = lane & 15, q = lane >> 4;
  const int row0 = blockIdx.x * 64;

  // ---- Aggregation into As: sum the 8 per-XCD sub-lists ----
  for (int j = tid; j < 64 * 12; j += 512) {
    int lr = j / 12, c = j % 12;  // c: 8-dim (16 B) chunk
    int r = row0 + lr;
    float acc[8];
#pragma unroll
    for (int k = 0; k < 8; ++k) acc[k] = 0.f;
    if (r < N) {
      const int2* epr = epad + (size_t)r * 128;
#pragma unroll
      for (int g = 0; g < 8; ++g) {
        int e1 = cnt8[(size_t)g * N + r];
        if (e1 > CAPG) e1 = CAPG;
        const int2* ep = epr + g * CAPG;
        int e = 0;
        for (; e + 2 <= e1; e += 2) {
          int2 p0 = ep[e + 0];
          int2 p1 = ep[e + 1];
          uint4 v0 = *(const uint4*)(newXb + (size_t)p0.x * DU + c * 8);
          uint4 v1 = *(const uint4*)(newXb + (size_t)p1.x * DU + c * 8);
          float a0 = __int_as_float(p0.y), a1 = __int_as_float(p1.y);
          acc[0] = fmaf(a0, __uint_as_float(v0.x << 16), acc[0]);
          acc[1] = fmaf(a0, __uint_as_float(v0.x & 0xFFFF0000u), acc[1]);
          acc[2] = fmaf(a0, __uint_as_float(v0.y << 16), acc[2]);
          acc[3] = fmaf(a0, __uint_as_float(v0.y & 0xFFFF0000u), acc[3]);
          acc[4] = fmaf(a0, __uint_as_float(v0.z << 16), acc[4]);
          acc[5] = fmaf(a0, __uint_as_float(v0.z & 0xFFFF0000u), acc[5]);
          acc[6] = fmaf(a0, __uint_as_float(v0.w << 16), acc[6]);
          acc[7] = fmaf(a0, __uint_as_float(v0.w & 0xFFFF0000u), acc[7]);
          acc[0] = fmaf(a1, __uint_as_float(v1.x << 16), acc[0]);
          acc[1] = fmaf(a1, __uint_as_float(v1.x & 0xFFFF0000u), acc[1]);
          acc[2] = fmaf(a1, __uint_as_float(v1.y << 16), acc[2]);
          acc[3] = fmaf(a1, __uint_as_float(v1.y & 0xFFFF0000u), acc[3]);
          acc[4] = fmaf(a1, __uint_as_float(v1.z << 16), acc[4]);
          acc[5] = fmaf(a1, __uint_as_float(v1.z & 0xFFFF0000u), acc[5]);
          acc[6] = fmaf(a1, __uint_as_float(v1.w << 16), acc[6]);
          acc[7] = fmaf(a1, __uint_as_float(v1.w & 0xFFFF0000u), acc[7]);
        }
        if (e < e1) {
          int2 p = ep[e];
          uint4 v = *(const uint4*)(newXb + (size_t)p.x * DU + c * 8);
          float a = __int_as_float(p.y);
          acc[0] = fmaf(a, __uint_as_float(v.x << 16), acc[0]);
          acc[1] = fmaf(a, __uint_as_float(v.x & 0xFFFF0000u), acc[1]);
          acc[2] = fmaf(a, __uint_as_float(v.y << 16), acc[2]);
          acc[3] = fmaf(a, __uint_as_float(v.y & 0xFFFF0000u), acc[3]);
          acc[4] = fmaf(a, __uint_as_float(v.z << 16), acc[4]);
          acc[5] = fmaf(a, __uint_as_float(v.z & 0xFFFF0000u), acc[5]);
          acc[6] = fmaf(a, __uint_as_float(v.w << 16), acc[6]);
          acc[7] = fmaf(a, __uint_as_float(v.w & 0xFFFF0000u), acc[7]);
        }
      }
    }
    uint4 o;
    o.x = bf16r(acc[0]) | (bf16r(acc[1]) << 16);
    o.y = bf16r(acc[2]) | (bf16r(acc[3]) << 16);
    o.z = bf16r(acc[4]) | (bf16r(acc[5]) << 16);
    o.w = bf16r(acc[6]) | (bf16r(acc[7]) << 16);
    *(uint4*)&As[lr][c * 8] = o;
  }
  __syncthreads();

  // ---- Gate MFMA: wave wv -> row-group rg = wv>>1, col-half ch = wv&1 ----
  {
    const int wv = tid >> 6;
    const int rg = wv >> 1;
    const int ch = wv & 1;
    int ar = row0 + rg * 16 + m;
    if (ar > N - 1) ar = N - 1;
    const int lr = rg * 16 + m;

    f32x4 acc[3];
#pragma unroll
    for (int t = 0; t < 3; ++t) acc[t] = (f32x4){0.f, 0.f, 0.f, 0.f};

#pragma unroll
    for (int ks = 0; ks < 3; ++ks) {
      short8 af = *(const short8*)(Xb + (size_t)ar * DU + ks * 32 + q * 8);
#pragma unroll
      for (int tt = 0; tt < 3; ++tt) {
        int t = ch * 3 + tt;
        short8 bf = *(const short8*)(WTgi + (size_t)(t * 16 + m) * DU + ks * 32 + q * 8);
        acc[tt] = __builtin_amdgcn_mfma_f32_16x16x32_bf16(af, bf, acc[tt], 0, 0, 0);
      }
    }
#pragma unroll
    for (int ks = 0; ks < 3; ++ks) {
      short8 af = *(const short8*)&As[lr][ks * 32 + q * 8];
#pragma unroll
      for (int tt = 0; tt < 3; ++tt) {
        int t = ch * 3 + tt;
        short8 bf = *(const short8*)(WTgn + (size_t)(t * 16 + m) * DU + ks * 32 + q * 8);
        acc[tt] = __builtin_amdgcn_mfma_f32_16x16x32_bf16(af, bf, acc[tt], 0, 0, 0);
      }
    }
#pragma unroll
    for (int tt = 0; tt < 3; ++tt) {
      int c = (ch * 3 + tt) * 16 + m;
      float bb = bgi[c] + bgn[c];
#pragma unroll
      for (int i = 0; i < 4; ++i) {
        float z = acc[tt][i] + bb;
        Gs[rg * 16 + q * 4 + i][c] = 1.f / (1.f + __expf(-z));
      }
    }
  }
  __syncthreads();

  // ---- Epilogue: out = x + g*(agg - x); agg from As (LDS) ----
  for (int j = tid; j < 64 * DU4; j += 512) {
    int r = j / DU4, c = j % DU4;
    int gr = row0 + r;
    if (gr < N) {
      float4 xv = ((const float4*)X)[(size_t)gr * DU4 + c];
      uint2 av = *(const uint2*)&As[r][c * 4];
      float a0 = __uint_as_float(av.x << 16);
      float a1 = __uint_as_float(av.x & 0xFFFF0000u);
      float a2 = __uint_as_float(av.y << 16);
      float a3 = __uint_as_float(av.y & 0xFFFF0000u);
      const float* gp = &Gs[r][c * 4];
      float4 o;
      o.x = xv.x + gp[0] * (a0 - xv.x);
      o.y = xv.y + gp[1] * (a1 - xv.y);
      o.z = xv.z + gp[2] * (a2 - xv.z);
      o.w = xv.w + gp[3] * (a3 - xv.w);
      ((float4*)Out)[(size_t)gr * DU4 + c] = o;
    }
  }
}

extern "C" void kernel_launch(void* const* d_in, const int* in_sizes, int n_in,
                              void* d_out, int out_size, void* d_ws, size_t ws_size,
                              hipStream_t stream) {
  const float* X      = (const float*)d_in[0];
  const float* a_vals = (const float*)d_in[1];
  const float* Wn     = (const float*)d_in[2];
  const float* bn     = (const float*)d_in[3];
  const float* Wgi    = (const float*)d_in[4];
  const float* bgi    = (const float*)d_in[5];
  const float* Wgn    = (const float*)d_in[6];
  const float* bgn    = (const float*)d_in[7];
  const int*   row    = (const int*)d_in[8];
  const int*   col    = (const int*)d_in[9];
  float* out = (float*)d_out;

  const int N = in_sizes[0] / DU;
  const int E = in_sizes[1];
  const int ntile = (N + 63) / 64;          // 782
  const int G1 = ((ntile + 7) / 8) * 8;     // 784, multiple of 8 for sub-counter groups

  // Workspace (~72 MB of 256 MiB): epad first for 16B alignment
  int2*   epad  = (int2*)d_ws;                        // N*128 + 128 guard (51.2 MB)
  ushort* Xb    = (ushort*)(epad + (size_t)N * 128 + 128);  // 9.6 MB
  ushort* newXb = Xb + (size_t)N * DU;                // 9.6 MB
  ushort* WTgi  = newXb + (size_t)N * DU;             // 18 KB
  ushort* WTgn  = WTgi + DU * DU;                     // 18 KB
  int*    cnt8  = (int*)(WTgn + DU * DU);             // 8*N ints (1.6 MB)

  hipMemsetAsync(cnt8, 0, (size_t)8 * N * sizeof(int), stream);

  k_fuse1<<<G1, 256, 0, stream>>>(X, Wn, bn, Wgi, Wgn, row, col, a_vals,
                                  Xb, newXb, WTgi, WTgn, cnt8, epad, N, E, ntile);
  k_aggGate<<<ntile, 512, 0, stream>>>(Xb, newXb, cnt8, epad, WTgi, WTgn,
                                       bgi, bgn, X, out, N);
}

// Round 11
// 187.476 us; speedup vs baseline: 1.1768x; 1.1768x over previous
//
#include <hip/hip_runtime.h>
#include <math.h>

// GatedGCN forward, fp32 in/out. D = U = 96. 4 dispatches:
//   memset(cnt) | k_fuse1: W-convert + Xb + newX MFMA + padded-CSR fill
//   | k_agg: gather-aggregate (uint4) | k_gateM: gate MFMA + combine.
// Evidence: R7 structure = best known (192.7us). R10 disproved the atomic-
// serialization theory (8-way sub-counters made fill slower); fill is bound
// by scattered-write L2-bounce/writeback throughput (~1 TB/s) - left as R7.
// R11 change: agg gathers 16B/request (12 thr/row) instead of 8B (24 thr/row)
// -> half the L2 requests for the same bytes. R6: no cooperative grid.sync.

#define DU 96
#define DU4 24
#define CAP 64  // slots per dest; Poisson(16) tail P(>=64) ~ 1e-22

typedef unsigned int uint;
typedef unsigned short ushort;
typedef __attribute__((ext_vector_type(8))) short short8;
typedef __attribute__((ext_vector_type(4))) float f32x4;

__device__ inline uint bf16r(float x) {  // fp32 -> bf16 bits, round-nearest-even
  uint u = __float_as_uint(x);
  return (u + 0x7FFFu + ((u >> 16) & 1u)) >> 16;
}

// ---------- k_fuse1: per-block W->LDS, X->Xs/Xb, newX MFMA, then CSR fill ----
__global__ __launch_bounds__(256) void k_fuse1(
    const float* __restrict__ X, const float* __restrict__ Wn,
    const float* __restrict__ bn, const float* __restrict__ Wgi,
    const float* __restrict__ Wgn, const int* __restrict__ row,
    const int* __restrict__ col, const float* __restrict__ a_vals,
    ushort* __restrict__ Xb, ushort* __restrict__ newXb,
    ushort* __restrict__ WTgi, ushort* __restrict__ WTgn,
    int* __restrict__ cnt, int2* __restrict__ epad, int N, int E, int ntile) {
  __shared__ ushort WL[9216];     // Wn bf16, MFMA-fragment-ordered (18 KB)
  __shared__ ushort Xs[64][104];  // X tile bf16 (13 KB); reused as Y staging
  const int tid = threadIdx.x;
  const int lane = tid & 63, w = tid >> 6;
  const int m = lane & 15, q = lane >> 4;

  if ((int)blockIdx.x < ntile) {
    // blocks 0/1: emit gate weights bf16 (row-major WT[n*96+k]) for k_gateM
    if (blockIdx.x == 0) {
      for (int i = tid; i < DU * DU; i += 256) {
        int n = i / DU, k = i % DU;
        WTgi[i] = (ushort)bf16r(Wgi[k * DU + n]);
      }
    } else if (blockIdx.x == 1) {
      for (int i = tid; i < DU * DU; i += 256) {
        int n = i / DU, k = i % DU;
        WTgn[i] = (ushort)bf16r(Wgn[k * DU + n]);
      }
    }
    // Wn -> WL in exact B-fragment order: frag (ks,t), lane, j ->
    // element k = ks*32+(lane>>4)*8+j, n = t*16+(lane&15)
    for (int idx = tid; idx < 9216; idx += 256) {
      int j = idx & 7, ln = (idx >> 3) & 63, tk = idx >> 9;  // tk = ks*6+t
      int ks = tk / 6, t = tk % 6;
      int k = ks * 32 + (ln >> 4) * 8 + j;
      int n = t * 16 + (ln & 15);
      WL[idx] = (ushort)bf16r(Wn[k * DU + n]);
    }
    // own 64 X rows -> Xs (LDS) + Xb (global)
    const int row0 = blockIdx.x * 64;
    for (int i = tid; i < 64 * 48; i += 256) {
      int r = i / 48, cu = i % 48;
      int gr = row0 + r;
      uint packed = 0;
      if (gr < N) {
        float2 v = ((const float2*)X)[(size_t)gr * 48 + cu];
        packed = bf16r(v.x) | (bf16r(v.y) << 16);
        ((uint*)Xb)[(size_t)gr * 48 + cu] = packed;
      }
      *(uint*)&Xs[r][cu * 2] = packed;
    }
    __syncthreads();

    f32x4 acc[6];
#pragma unroll
    for (int t = 0; t < 6; ++t) acc[t] = (f32x4){0.f, 0.f, 0.f, 0.f};
#pragma unroll
    for (int ks = 0; ks < 3; ++ks) {
      short8 af = *(const short8*)&Xs[w * 16 + m][ks * 32 + q * 8];
#pragma unroll
      for (int t = 0; t < 6; ++t) {
        short8 bf = *(const short8*)&WL[((ks * 6 + t) * 64 + lane) * 8];
        acc[t] = __builtin_amdgcn_mfma_f32_16x16x32_bf16(af, bf, acc[t], 0, 0, 0);
      }
    }
    __syncthreads();  // all A-frag reads done; reuse Xs as output staging
#pragma unroll
    for (int t = 0; t < 6; ++t) {
      int c = t * 16 + m;
      float bb = bn[c];
#pragma unroll
      for (int i = 0; i < 4; ++i)
        Xs[w * 16 + q * 4 + i][c] = (ushort)bf16r(acc[t][i] + bb);
    }
    __syncthreads();
    for (int i = tid; i < 64 * 48; i += 256) {
      int r = i / 48, cu = i % 48;
      int gr = row0 + r;
      if (gr < N) ((uint*)newXb)[(size_t)gr * 48 + cu] = *(uint*)&Xs[r][cu * 2];
    }
  }

  // Padded-CSR fill, XCD-partitioned by dest range (g = blockIdx&7 -> same XCD
  // under round-robin dispatch); each group re-scans all edges (reads are
  // L2/L3-hot, cheap) and handles only its 1/8 dest range. Bound by
  // scattered-write throughput (~1 TB/s on writeback) - R8/R9/R10 layout
  // variants all regressed; this is the best-measured form.
  {
    const int g = blockIdx.x & 7;
    const int sub = blockIdx.x >> 3;
    const int nsub = gridDim.x >> 3;
    const int d0 = (int)((long long)N * g >> 3);
    const int d1 = (int)((long long)N * (g + 1) >> 3);
    for (int i = sub * 256 + tid; i < E; i += nsub * 256) {
      int d = row[i];
      if (d >= d0 && d < d1) {
        int slot = atomicAdd(&cnt[d], 1);
        epad[(size_t)d * CAP + slot] = make_int2(col[i], __float_as_int(a_vals[i]));
      }
    }
  }
}

// ---------- k_agg: aggb[r] = bf16(sum_e a_e * newXb[col_e]) ----------
// One thread per (row, 8-dim 16B chunk): 12 threads/row, uint4 gathers,
// unroll-4 (4 gathers in flight). Half the L2 requests of the uint2 version.
__global__ __launch_bounds__(256) void k_agg(const ushort* __restrict__ newXb,
                                             const int* __restrict__ cnt,
                                             const int2* __restrict__ epad,
                                             ushort* __restrict__ aggb, int N) {
  int i = blockIdx.x * 256 + threadIdx.x;
  int r = i / 12;
  int c = i % 12;  // dims c*8 .. c*8+7
  if (r >= N) return;
  int e1 = cnt[r];
  if (e1 > CAP) e1 = CAP;
  const int2* ep = epad + (size_t)r * CAP;
  float accA[8], accB[8];
#pragma unroll
  for (int k = 0; k < 8; ++k) { accA[k] = 0.f; accB[k] = 0.f; }
  int e = 0;
  for (; e + 4 <= e1; e += 4) {
    int2 p0 = ep[e + 0];
    int2 p1 = ep[e + 1];
    int2 p2 = ep[e + 2];
    int2 p3 = ep[e + 3];
    uint4 v0 = *(const uint4*)(newXb + (size_t)p0.x * DU + c * 8);
    uint4 v1 = *(const uint4*)(newXb + (size_t)p1.x * DU + c * 8);
    uint4 v2 = *(const uint4*)(newXb + (size_t)p2.x * DU + c * 8);
    uint4 v3 = *(const uint4*)(newXb + (size_t)p3.x * DU + c * 8);
    float a0 = __int_as_float(p0.y), a1 = __int_as_float(p1.y);
    float a2 = __int_as_float(p2.y), a3 = __int_as_float(p3.y);
    accA[0] = fmaf(a0, __uint_as_float(v0.x << 16), accA[0]);
    accA[1] = fmaf(a0, __uint_as_float(v0.x & 0xFFFF0000u), accA[1]);
    accA[2] = fmaf(a0, __uint_as_float(v0.y << 16), accA[2]);
    accA[3] = fmaf(a0, __uint_as_float(v0.y & 0xFFFF0000u), accA[3]);
    accA[4] = fmaf(a0, __uint_as_float(v0.z << 16), accA[4]);
    accA[5] = fmaf(a0, __uint_as_float(v0.z & 0xFFFF0000u), accA[5]);
    accA[6] = fmaf(a0, __uint_as_float(v0.w << 16), accA[6]);
    accA[7] = fmaf(a0, __uint_as_float(v0.w & 0xFFFF0000u), accA[7]);
    accB[0] = fmaf(a1, __uint_as_float(v1.x << 16), accB[0]);
    accB[1] = fmaf(a1, __uint_as_float(v1.x & 0xFFFF0000u), accB[1]);
    accB[2] = fmaf(a1, __uint_as_float(v1.y << 16), accB[2]);
    accB[3] = fmaf(a1, __uint_as_float(v1.y & 0xFFFF0000u), accB[3]);
    accB[4] = fmaf(a1, __uint_as_float(v1.z << 16), accB[4]);
    accB[5] = fmaf(a1, __uint_as_float(v1.z & 0xFFFF0000u), accB[5]);
    accB[6] = fmaf(a1, __uint_as_float(v1.w << 16), accB[6]);
    accB[7] = fmaf(a1, __uint_as_float(v1.w & 0xFFFF0000u), accB[7]);
    accA[0] = fmaf(a2, __uint_as_float(v2.x << 16), accA[0]);
    accA[1] = fmaf(a2, __uint_as_float(v2.x & 0xFFFF0000u), accA[1]);
    accA[2] = fmaf(a2, __uint_as_float(v2.y << 16), accA[2]);
    accA[3] = fmaf(a2, __uint_as_float(v2.y & 0xFFFF0000u), accA[3]);
    accA[4] = fmaf(a2, __uint_as_float(v2.z << 16), accA[4]);
    accA[5] = fmaf(a2, __uint_as_float(v2.z & 0xFFFF0000u), accA[5]);
    accA[6] = fmaf(a2, __uint_as_float(v2.w << 16), accA[6]);
    accA[7] = fmaf(a2, __uint_as_float(v2.w & 0xFFFF0000u), accA[7]);
    accB[0] = fmaf(a3, __uint_as_float(v3.x << 16), accB[0]);
    accB[1] = fmaf(a3, __uint_as_float(v3.x & 0xFFFF0000u), accB[1]);
    accB[2] = fmaf(a3, __uint_as_float(v3.y << 16), accB[2]);
    accB[3] = fmaf(a3, __uint_as_float(v3.y & 0xFFFF0000u), accB[3]);
    accB[4] = fmaf(a3, __uint_as_float(v3.z << 16), accB[4]);
    accB[5] = fmaf(a3, __uint_as_float(v3.z & 0xFFFF0000u), accB[5]);
    accB[6] = fmaf(a3, __uint_as_float(v3.w << 16), accB[6]);
    accB[7] = fmaf(a3, __uint_as_float(v3.w & 0xFFFF0000u), accB[7]);
  }
  for (; e < e1; ++e) {
    int2 p = ep[e];
    uint4 v = *(const uint4*)(newXb + (size_t)p.x * DU + c * 8);
    float a = __int_as_float(p.y);
    accA[0] = fmaf(a, __uint_as_float(v.x << 16), accA[0]);
    accA[1] = fmaf(a, __uint_as_float(v.x & 0xFFFF0000u), accA[1]);
    accA[2] = fmaf(a, __uint_as_float(v.y << 16), accA[2]);
    accA[3] = fmaf(a, __uint_as_float(v.y & 0xFFFF0000u), accA[3]);
    accA[4] = fmaf(a, __uint_as_float(v.z << 16), accA[4]);
    accA[5] = fmaf(a, __uint_as_float(v.z & 0xFFFF0000u), accA[5]);
    accA[6] = fmaf(a, __uint_as_float(v.w << 16), accA[6]);
    accA[7] = fmaf(a, __uint_as_float(v.w & 0xFFFF0000u), accA[7]);
  }
#pragma unroll
  for (int k = 0; k < 8; ++k) accA[k] += accB[k];
  uint4 o;
  o.x = bf16r(accA[0]) | (bf16r(accA[1]) << 16);
  o.y = bf16r(accA[2]) | (bf16r(accA[3]) << 16);
  o.z = bf16r(accA[4]) | (bf16r(accA[5]) << 16);
  o.w = bf16r(accA[6]) | (bf16r(accA[7]) << 16);
  *(uint4*)(aggb + (size_t)r * DU + c * 8) = o;
}

// ---------- k_gateM: z = Xb@Wgi + aggb@Wgn + b; out = X + g*(agg-X) ----------
__global__ __launch_bounds__(256) void k_gateM(const ushort* __restrict__ Xb,
                                               const ushort* __restrict__ aggb,
                                               const ushort* __restrict__ WTgi,
                                               const ushort* __restrict__ WTgn,
                                               const float* __restrict__ bgi,
                                               const float* __restrict__ bgn,
                                               const float* __restrict__ X,
                                               float* __restrict__ Out, int N) {
  __shared__ float Gs[64][100];
  const int tid = threadIdx.x;
  const int lane = tid & 63, w = tid >> 6;
  const int m = lane & 15, q = lane >> 4;
  const int row0 = blockIdx.x * 64;
  int ar = row0 + w * 16 + m;
  if (ar > N - 1) ar = N - 1;

  f32x4 acc[6];
#pragma unroll
  for (int t = 0; t < 6; ++t) acc[t] = (f32x4){0.f, 0.f, 0.f, 0.f};

#pragma unroll
  for (int ks = 0; ks < 3; ++ks) {
    short8 af = *(const short8*)(Xb + (size_t)ar * DU + ks * 32 + q * 8);
#pragma unroll
    for (int t = 0; t < 6; ++t) {
      short8 bf = *(const short8*)(WTgi + (size_t)(t * 16 + m) * DU + ks * 32 + q * 8);
      acc[t] = __builtin_amdgcn_mfma_f32_16x16x32_bf16(af, bf, acc[t], 0, 0, 0);
    }
  }
#pragma unroll
  for (int ks = 0; ks < 3; ++ks) {
    short8 af = *(const short8*)(aggb + (size_t)ar * DU + ks * 32 + q * 8);
#pragma unroll
    for (int t = 0; t < 6; ++t) {
      short8 bf = *(const short8*)(WTgn + (size_t)(t * 16 + m) * DU + ks * 32 + q * 8);
      acc[t] = __builtin_amdgcn_mfma_f32_16x16x32_bf16(af, bf, acc[t], 0, 0, 0);
    }
  }

#pragma unroll
  for (int t = 0; t < 6; ++t) {
    int c = t * 16 + m;
    float bb = bgi[c] + bgn[c];
#pragma unroll
    for (int i = 0; i < 4; ++i) {
      float z = acc[t][i] + bb;
      Gs[w * 16 + q * 4 + i][c] = 1.f / (1.f + __expf(-z));
    }
  }
  __syncthreads();

  for (int j = tid; j < 64 * DU4; j += 256) {
    int r = j / DU4, c = j % DU4;
    int gr = row0 + r;
    if (gr < N) {
      float4 xv = ((const float4*)X)[(size_t)gr * DU4 + c];
      uint2 av = ((const uint2*)aggb)[(size_t)gr * DU4 + c];
      float a0 = __uint_as_float(av.x << 16);
      float a1 = __uint_as_float(av.x & 0xFFFF0000u);
      float a2 = __uint_as_float(av.y << 16);
      float a3 = __uint_as_float(av.y & 0xFFFF0000u);
      const float* gp = &Gs[r][c * 4];
      float4 o;
      o.x = xv.x + gp[0] * (a0 - xv.x);
      o.y = xv.y + gp[1] * (a1 - xv.y);
      o.z = xv.z + gp[2] * (a2 - xv.z);
      o.w = xv.w + gp[3] * (a3 - xv.w);
      ((float4*)Out)[(size_t)gr * DU4 + c] = o;
    }
  }
}

extern "C" void kernel_launch(void* const* d_in, const int* in_sizes, int n_in,
                              void* d_out, int out_size, void* d_ws, size_t ws_size,
                              hipStream_t stream) {
  const float* X      = (const float*)d_in[0];
  const float* a_vals = (const float*)d_in[1];
  const float* Wn     = (const float*)d_in[2];
  const float* bn     = (const float*)d_in[3];
  const float* Wgi    = (const float*)d_in[4];
  const float* bgi    = (const float*)d_in[5];
  const float* Wgn    = (const float*)d_in[6];
  const float* bgn    = (const float*)d_in[7];
  const int*   row    = (const int*)d_in[8];
  const int*   col    = (const int*)d_in[9];
  float* out = (float*)d_out;

  const int N = in_sizes[0] / DU;
  const int E = in_sizes[1];
  const int ntile = (N + 63) / 64;          // 782
  const int G1 = ((ntile + 7) / 8) * 8;     // 784, multiple of 8 for XCD fill

  // Workspace (~55 MB of 256 MiB): epad first for 16B alignment
  int2*   epad  = (int2*)d_ws;                        // N*CAP + CAP guard (25.6 MB)
  ushort* Xb    = (ushort*)(epad + (size_t)N * CAP + CAP);  // 9.6 MB
  ushort* newXb = Xb + (size_t)N * DU;                // 9.6 MB
  ushort* aggb  = newXb + (size_t)N * DU;             // 9.6 MB
  ushort* WTgi  = aggb + (size_t)N * DU;              // 18 KB
  ushort* WTgn  = WTgi + DU * DU;                     // 18 KB
  int*    cnt   = (int*)(WTgn + DU * DU);             // N ints

  hipMemsetAsync(cnt, 0, (size_t)N * sizeof(int), stream);

  k_fuse1<<<G1, 256, 0, stream>>>(X, Wn, bn, Wgi, Wgn, row, col, a_vals,
                                  Xb, newXb, WTgi, WTgn, cnt, epad, N, E, ntile);
  k_agg  <<<((size_t)N * 12 + 255) / 256, 256, 0, stream>>>(newXb, cnt, epad, aggb, N);
  k_gateM<<<ntile, 256, 0, stream>>>(Xb, aggb, WTgi, WTgn, bgi, bgn, X, out, N);
}